// Round 6
// baseline (143671.313 us; speedup 1.0000x reference)
//
#include <hip/hip_runtime.h>

#define HH 512
#define OO 256
#define BB 64
#define SS 1024
#define TT 256
#define KK 1280   // H(ctx) + O(target) + H(h)

typedef __attribute__((ext_vector_type(8))) short bh8;
typedef __attribute__((ext_vector_type(4))) float fx4;

__device__ __forceinline__ unsigned short f2bf(float x) {
    union { float f; unsigned int u; } v; v.f = x;
    unsigned int r = v.u + 0x7fffu + ((v.u >> 16) & 1u);
    return (unsigned short)(r >> 16);
}

// Pack W_cat = [W_ih | W_hh] (j-permuted so each h-tile block owns its 4 gates)
// into MFMA B-fragment-major bf16 layout. See round-0 comment for indexing.
__global__ void prep_weights(const float* __restrict__ W_ih,
                             const float* __restrict__ W_hh,
                             unsigned short* __restrict__ wfrag) {
    int g = blockIdx.x * 256 + threadIdx.x;     // 64*40*2*64 = 327680 groups
    if (g >= 64 * 40 * 2 * 64) return;
    int lane = g & 63;
    int nt = (g >> 6) & 1;
    int kk = (g >> 7) % 40;
    int ht = (g >> 7) / 40;
    int c = nt * 16 + (lane & 15);
    int gate = c >> 3, rr = c & 7;
    int j = gate * 512 + ht * 8 + rr;
    int kbase = kk * 32 + (lane >> 4) * 8;
    unsigned short* dst = wfrag + (size_t)g * 8;
#pragma unroll
    for (int r = 0; r < 8; ++r) {
        int k = kbase + r;
        float v = (k < 768) ? W_ih[(size_t)j * 768 + k]
                            : W_hh[(size_t)j * 512 + (k - 768)];
        dst[r] = f2bf(v);
    }
}

__global__ void prep_misc(const float* __restrict__ hidden,
                          const float* __restrict__ cell,
                          float* __restrict__ h, float* __restrict__ c,
                          int* __restrict__ cnt, int* __restrict__ done) {
    const int total = 32768 + 32768 + 64 + 512;
    for (int i = blockIdx.x * 256 + threadIdx.x; i < total; i += gridDim.x * 256) {
        if (i < 32768) {
            h[i] = hidden[i];
        } else if (i < 65536) {
            c[i - 32768] = cell[i - 32768];
        } else if (i < 65600) {
            cnt[i - 65536] = 0;
        } else {
            done[i - 65600] = 0;       // done_x[256] ++ done_h[256]
        }
    }
}

__device__ __forceinline__ void wait_ge(const int* p, int n) {
    if (threadIdx.x == 0) {
        int v;
        do {
            v = __hip_atomic_load(p, __ATOMIC_ACQUIRE, __HIP_MEMORY_SCOPE_AGENT);
            if (v < n) __builtin_amdgcn_s_sleep(16);
        } while (v < n);
    }
    __syncthreads();
}

// FC for one (b, oq) unit; reads W_fc rows directly (summation order as R4/R5).
__device__ __forceinline__ void fc_unit(int v, int tprev,
                                        const float* __restrict__ h,
                                        const float* __restrict__ W_fc,
                                        const float* __restrict__ b_fc,
                                        float* __restrict__ out,
                                        float (*shacc)[64]) {
    const int tid = threadIdx.x;
    const int b = v >> 2, oq = v & 3;
    const int ol = tid & 63, kq = tid >> 6;
    const int o = oq * 64 + ol;
    float acc = 0.f;
    const float* hp = h + b * HH + kq * 128;
    const float* wp = W_fc + (size_t)o * HH + kq * 128;
#pragma unroll 8
    for (int k2 = 0; k2 < 128; ++k2) acc += hp[k2] * wp[k2];
    shacc[kq][ol] = acc;
    __syncthreads();
    if (tid < 64) {
        float vv = shacc[0][tid] + shacc[1][tid]
                 + shacc[2][tid] + shacc[3][tid] + b_fc[oq * 64 + tid];
        out[((size_t)b * TT + tprev) * OO + oq * 64 + tid] = vv;
    }
    __syncthreads();
}

// Persistent kernel: 1024 blocks, each owns attention unit (b, ch) for all t.
// Blocks 0..63 additionally run gates (ht = bid); blocks 64..319 run FC(t-1).
// Sync: done_x[t] (64 combines -> xb ready), done_h[t] (64 gate tiles -> h ready).
__global__ void __launch_bounds__(256, 4)
decoder_persist(const float* __restrict__ enc, const float* __restrict__ target,
                float* __restrict__ hA, float* __restrict__ hB,
                float* __restrict__ c,
                unsigned short* __restrict__ xb,
                float* __restrict__ pm, float* __restrict__ pl,
                float* __restrict__ pctx, int* __restrict__ cnt,
                int* __restrict__ done_x, int* __restrict__ done_h,
                const unsigned short* __restrict__ wfrag,
                const float* __restrict__ b_ih, const float* __restrict__ b_hh,
                const float* __restrict__ W_fc, const float* __restrict__ b_fc,
                float* __restrict__ out) {
    const int tid = threadIdx.x;
    const int lane = tid & 63;
    const int w = tid >> 6;
    const int bid = blockIdx.x;
    const int b = bid >> 4, ch = bid & 15;

    __shared__ union {
        struct { float m[4]; float l[4]; float ctx[4][512]; int flag; } a;
        struct { float acc[4][64]; } o;
        struct { float g[64][32]; } bg;
    } sh;

    for (int t = 0; t < TT; ++t) {
        const float* hcur = (t & 1) ? hB : hA;
        float* hnxt = (t & 1) ? hA : hB;
        if (t > 0) wait_ge(&done_h[t - 1], 64);

        // ---------------- attention for (b, ch) ----------------
        {
            const float4 h0 = *(const float4*)(hcur + b * HH + lane * 4);
            const float4 h1 = *(const float4*)(hcur + b * HH + 256 + lane * 4);
            float m = -3.0e38f, l = 0.f;
            float4 c0 = {0, 0, 0, 0}, c1 = {0, 0, 0, 0};
            const float* er = enc + ((size_t)(b * SS + ch * 64 + w * 16)) * HH;
            for (int rp = 0; rp < 8; ++rp) {
                const float4 e0 = *(const float4*)(er + lane * 4);
                const float4 e1 = *(const float4*)(er + 256 + lane * 4);
                const float4 f0 = *(const float4*)(er + HH + lane * 4);
                const float4 f1 = *(const float4*)(er + HH + 256 + lane * 4);
                float dA = e0.x * h0.x + e0.y * h0.y + e0.z * h0.z + e0.w * h0.w
                         + e1.x * h1.x + e1.y * h1.y + e1.z * h1.z + e1.w * h1.w;
                float dB = f0.x * h0.x + f0.y * h0.y + f0.z * h0.z + f0.w * h0.w
                         + f1.x * h1.x + f1.y * h1.y + f1.z * h1.z + f1.w * h1.w;
#pragma unroll
                for (int off = 32; off; off >>= 1) {
                    dA += __shfl_xor(dA, off);
                    dB += __shfl_xor(dB, off);
                }
                const float mx = fmaxf(dA, dB);
                if (mx > m) {                      // wave-uniform branch
                    const float fs = __expf(m - mx);
                    l *= fs;
                    c0.x *= fs; c0.y *= fs; c0.z *= fs; c0.w *= fs;
                    c1.x *= fs; c1.y *= fs; c1.z *= fs; c1.w *= fs;
                    m = mx;
                }
                const float pA = __expf(dA - m);
                const float pB = __expf(dB - m);
                l += pA + pB;
                c0.x += pA * e0.x + pB * f0.x; c0.y += pA * e0.y + pB * f0.y;
                c0.z += pA * e0.z + pB * f0.z; c0.w += pA * e0.w + pB * f0.w;
                c1.x += pA * e1.x + pB * f1.x; c1.y += pA * e1.y + pB * f1.y;
                c1.z += pA * e1.z + pB * f1.z; c1.w += pA * e1.w + pB * f1.w;
                er += 2 * HH;
            }
            if (lane == 0) { sh.a.m[w] = m; sh.a.l[w] = l; }
            *(float4*)&sh.a.ctx[w][lane * 4] = c0;
            *(float4*)&sh.a.ctx[w][256 + lane * 4] = c1;
            __syncthreads();
            float M = fmaxf(fmaxf(sh.a.m[0], sh.a.m[1]), fmaxf(sh.a.m[2], sh.a.m[3]));
            float wg[4]; float ls = 0.f;
#pragma unroll
            for (int q = 0; q < 4; ++q) { wg[q] = __expf(sh.a.m[q] - M); ls += wg[q] * sh.a.l[q]; }
            const int hh = tid * 2;
            float v0 = wg[0] * sh.a.ctx[0][hh] + wg[1] * sh.a.ctx[1][hh]
                     + wg[2] * sh.a.ctx[2][hh] + wg[3] * sh.a.ctx[3][hh];
            float v1 = wg[0] * sh.a.ctx[0][hh + 1] + wg[1] * sh.a.ctx[1][hh + 1]
                     + wg[2] * sh.a.ctx[2][hh + 1] + wg[3] * sh.a.ctx[3][hh + 1];
            float* pc = pctx + ((size_t)(b * 16 + ch)) * HH;
            *(float2*)(pc + hh) = make_float2(v0, v1);
            if (tid == 0) { pm[b * 16 + ch] = M; pl[b * 16 + ch] = ls; }
            __threadfence();
            __syncthreads();
            if (tid == 0) sh.a.flag = atomicAdd(&cnt[b], 1);
            __syncthreads();
            if (sh.a.flag == 15) {
                // last block for b: combine 16 chunk partials -> x_bf16
                __threadfence();
                float Mb = -3.0e38f;
#pragma unroll
                for (int q2 = 0; q2 < 16; ++q2) Mb = fmaxf(Mb, pm[b * 16 + q2]);
                float wq[16]; float lsb = 0.f;
#pragma unroll
                for (int q2 = 0; q2 < 16; ++q2) {
                    wq[q2] = __expf(pm[b * 16 + q2] - Mb);
                    lsb += wq[q2] * pl[b * 16 + q2];
                }
                const float inv = 1.0f / lsb;
                const int h2 = tid * 2;
                float s0 = 0.f, s1 = 0.f;
#pragma unroll
                for (int q2 = 0; q2 < 16; ++q2) {
                    const float* pc2 = pctx + ((size_t)(b * 16 + q2)) * HH + h2;
                    s0 += wq[q2] * pc2[0];
                    s1 += wq[q2] * pc2[1];
                }
                xb[b * KK + h2]     = f2bf(s0 * inv);
                xb[b * KK + h2 + 1] = f2bf(s1 * inv);
                if (tid < 128) {
                    const float* tg = target + ((size_t)b * TT + t) * OO + tid * 2;
                    xb[b * KK + 512 + tid * 2]     = f2bf(tg[0]);
                    xb[b * KK + 512 + tid * 2 + 1] = f2bf(tg[1]);
                }
                xb[b * KK + 768 + h2]     = f2bf(hcur[b * HH + h2]);
                xb[b * KK + 768 + h2 + 1] = f2bf(hcur[b * HH + h2 + 1]);
                __syncthreads();               // all xb writes of this block done
                __threadfence();               // ... and flushed
                if (tid == 0) {
                    cnt[b] = 0;                // re-arm for next step
                    __hip_atomic_fetch_add(&done_x[t], 1, __ATOMIC_RELEASE,
                                           __HIP_MEMORY_SCOPE_AGENT);
                }
            }
        }

        // ---------------- FC for out[t-1] (off critical path) ----------------
        if (bid >= 64 && bid < 320 && t > 0)
            fc_unit(bid - 64, t - 1, hcur, W_fc, b_fc, out, sh.o.acc);

        // ---------------- gates for ht = bid ----------------
        if (bid < 64) {
            wait_ge(&done_x[t], 64);
            const int ht = bid;
            fx4 a0 = {0, 0, 0, 0}, a1 = {0, 0, 0, 0};
            const int bro = 16 * w + (lane & 15);
            const int kg = lane >> 4;
            const unsigned short* wf = wfrag + ((size_t)ht * 40 * 2) * 512;
            for (int kk = 0; kk < 40; ++kk) {
                bh8 av = *(const bh8*)(xb + (size_t)bro * KK + kk * 32 + kg * 8);
                bh8 b0 = *(const bh8*)(wf + (kk * 2 + 0) * 512 + lane * 8);
                bh8 b1 = *(const bh8*)(wf + (kk * 2 + 1) * 512 + lane * 8);
                a0 = __builtin_amdgcn_mfma_f32_16x16x32_bf16(av, b0, a0, 0, 0, 0);
                a1 = __builtin_amdgcn_mfma_f32_16x16x32_bf16(av, b1, a1, 0, 0, 0);
            }
            const int crow = (lane >> 4) * 4;
#pragma unroll
            for (int r = 0; r < 4; ++r) {
                sh.bg.g[16 * w + crow + r][lane & 15]        = a0[r];
                sh.bg.g[16 * w + crow + r][16 + (lane & 15)] = a1[r];
            }
            __syncthreads();
#pragma unroll
            for (int p = 0; p < 2; ++p) {
                const int idx = tid * 2 + p;
                const int rb = idx >> 3, r = idx & 7;
                const int hidx = ht * 8 + r;
                float gi = sh.bg.g[rb][r]      + b_ih[hidx]        + b_hh[hidx];
                float gf = sh.bg.g[rb][8 + r]  + b_ih[512 + hidx]  + b_hh[512 + hidx];
                float gg = sh.bg.g[rb][16 + r] + b_ih[1024 + hidx] + b_hh[1024 + hidx];
                float go = sh.bg.g[rb][24 + r] + b_ih[1536 + hidx] + b_hh[1536 + hidx];
                float ig = 1.f / (1.f + __expf(-gi));
                float fg = 1.f / (1.f + __expf(-gf));
                float g2 = tanhf(gg);
                float og = 1.f / (1.f + __expf(-go));
                float cn = fg * c[rb * HH + hidx] + ig * g2;
                float hn = og * tanhf(cn);
                c[rb * HH + hidx] = cn;
                hnxt[rb * HH + hidx] = hn;
            }
            __syncthreads();
            __threadfence();
            if (tid == 0)
                __hip_atomic_fetch_add(&done_h[t], 1, __ATOMIC_RELEASE,
                                       __HIP_MEMORY_SCOPE_AGENT);
        }
    }

    // epilogue: out[TT-1] from h(TT) (= hA, since TT even)
    if (bid >= 64 && bid < 320) {
        wait_ge(&done_h[TT - 1], 64);
        fc_unit(bid - 64, TT - 1, hA, W_fc, b_fc, out, sh.o.acc);
    }
}

extern "C" void kernel_launch(void* const* d_in, const int* in_sizes, int n_in,
                              void* d_out, int out_size, void* d_ws, size_t ws_size,
                              hipStream_t stream) {
    const float* enc    = (const float*)d_in[0];
    const float* hidden = (const float*)d_in[1];
    const float* cellp  = (const float*)d_in[2];
    const float* target = (const float*)d_in[3];
    const float* W_ih   = (const float*)d_in[4];
    const float* W_hh   = (const float*)d_in[5];
    const float* b_ih   = (const float*)d_in[6];
    const float* b_hh   = (const float*)d_in[7];
    const float* W_fc   = (const float*)d_in[8];
    const float* b_fc   = (const float*)d_in[9];
    float* out = (float*)d_out;

    char* base = (char*)d_ws;
    float* hA             = (float*)(base + 0);          // 64*512 f32
    float* hB             = (float*)(base + 131072);     // 64*512 f32
    float* c              = (float*)(base + 262144);     // 64*512 f32
    unsigned short* wfrag = (unsigned short*)(base + 393216);   // 5,242,880 B
    unsigned short* xb    = (unsigned short*)(base + 5636096);  // 64*1280 bf16
    float* pm             = (float*)(base + 5799936);    // 64*16
    float* pl             = (float*)(base + 5804032);    // 64*16
    float* pctx           = (float*)(base + 5808128);    // 64*16*512 f32
    int* cnt              = (int*)(base + 7905280);      // 64 ints
    int* done_x           = (int*)(base + 7905536);      // 256 ints
    int* done_h           = (int*)(base + 7906560);      // 256 ints

    hipLaunchKernelGGL(prep_weights, dim3(1280), dim3(256), 0, stream, W_ih, W_hh, wfrag);
    hipLaunchKernelGGL(prep_misc, dim3(256), dim3(256), 0, stream,
                       hidden, cellp, hA, c, cnt, done_x);   // done_x..done_h contiguous

    hipLaunchKernelGGL(decoder_persist, dim3(1024), dim3(256), 0, stream,
                       enc, target, hA, hB, c, xb, pm, pl, pctx,
                       cnt, done_x, done_h, wfrag, b_ih, b_hh, W_fc, b_fc, out);
}

// Round 7
// 10938.596 us; speedup vs baseline: 13.1343x; 13.1343x over previous
//
#include <hip/hip_runtime.h>

#define HH 512
#define OO 256
#define BB 64
#define SS 1024
#define TT 256
#define KK 1280   // H(ctx) + O(target) + H(h)

typedef __attribute__((ext_vector_type(8))) short bh8;
typedef __attribute__((ext_vector_type(4))) float fx4;

__device__ __forceinline__ unsigned short f2bf(float x) {
    union { float f; unsigned int u; } v; v.f = x;
    unsigned int r = v.u + 0x7fffu + ((v.u >> 16) & 1u);
    return (unsigned short)(r >> 16);
}

// Pack W_cat = [W_ih | W_hh] (j-permuted so each h-tile block owns its 4 gates)
// into MFMA B-fragment-major bf16 layout. See round-0 comment for indexing.
__global__ void prep_weights(const float* __restrict__ W_ih,
                             const float* __restrict__ W_hh,
                             unsigned short* __restrict__ wfrag) {
    int g = blockIdx.x * 256 + threadIdx.x;     // 64*40*2*64 = 327680 groups
    if (g >= 64 * 40 * 2 * 64) return;
    int lane = g & 63;
    int nt = (g >> 6) & 1;
    int kk = (g >> 7) % 40;
    int ht = (g >> 7) / 40;
    int c = nt * 16 + (lane & 15);
    int gate = c >> 3, rr = c & 7;
    int j = gate * 512 + ht * 8 + rr;
    int kbase = kk * 32 + (lane >> 4) * 8;
    unsigned short* dst = wfrag + (size_t)g * 8;
#pragma unroll
    for (int r = 0; r < 8; ++r) {
        int k = kbase + r;
        float v = (k < 768) ? W_ih[(size_t)j * 768 + k]
                            : W_hh[(size_t)j * 512 + (k - 768)];
        dst[r] = f2bf(v);
    }
}

__global__ void prep_misc(const float* __restrict__ hidden,
                          const float* __restrict__ cell,
                          float* __restrict__ h, float* __restrict__ c) {
    const int total = 32768 + 32768;
    for (int i = blockIdx.x * 256 + threadIdx.x; i < total; i += gridDim.x * 256) {
        if (i < 32768) h[i] = hidden[i];
        else           c[i - 32768] = cell[i - 32768];
    }
}

// FC for one (b, oq) unit; reads W_fc rows directly (summation order as R4-R6).
__device__ __forceinline__ void fc_unit(int v, int tprev,
                                        const float* __restrict__ h,
                                        const float* __restrict__ W_fc,
                                        const float* __restrict__ b_fc,
                                        float* __restrict__ out,
                                        float (*shacc)[64]) {
    const int tid = threadIdx.x;
    const int b = v >> 2, oq = v & 3;
    const int ol = tid & 63, kq = tid >> 6;
    const int o = oq * 64 + ol;
    float acc = 0.f;
    const float* hp = h + b * HH + kq * 128;
    const float* wp = W_fc + (size_t)o * HH + kq * 128;
#pragma unroll 8
    for (int k2 = 0; k2 < 128; ++k2) acc += hp[k2] * wp[k2];
    shacc[kq][ol] = acc;
    __syncthreads();
    if (tid < 64) {
        float vv = shacc[0][tid] + shacc[1][tid]
                 + shacc[2][tid] + shacc[3][tid] + b_fc[oq * 64 + tid];
        out[((size_t)b * TT + tprev) * OO + oq * 64 + tid] = vv;
    }
}

// Fence-free attention partials. Blocks 0..1023: unit (b, ch) writes its
// (m, l, ctx) partial to pm/pl/pctx — no atomics, no fences, no combine.
// Blocks 1024..1279: FC producing out[t-1] (reads only h). Visibility to the
// next kernel is carried by the kernel-boundary release/acquire.
__global__ void __launch_bounds__(256)
step_attnp(int t, const float* __restrict__ enc, const float* __restrict__ h,
           float* __restrict__ pm, float* __restrict__ pl,
           float* __restrict__ pctx,
           const float* __restrict__ W_fc, const float* __restrict__ b_fc,
           float* __restrict__ out) {
    const int tid = threadIdx.x;
    const int lane = tid & 63;
    const int w = tid >> 6;

    __shared__ union {
        struct { float m[4]; float l[4]; float ctx[4][512]; } a;
        struct { float acc[4][64]; } o;
    } sh;

    const int u = blockIdx.x;
    if (u < 1024) {
        const int b = u >> 4, ch = u & 15;
        const float4 h0 = *(const float4*)(h + b * HH + lane * 4);
        const float4 h1 = *(const float4*)(h + b * HH + 256 + lane * 4);
        float m = -3.0e38f, l = 0.f;
        float4 c0 = {0, 0, 0, 0}, c1 = {0, 0, 0, 0};
        const float* er = enc + ((size_t)(b * SS + ch * 64 + w * 16)) * HH;
        // pairwise rows: two independent dot-reduces in flight per iteration
        for (int rp = 0; rp < 8; ++rp) {
            const float4 e0 = *(const float4*)(er + lane * 4);
            const float4 e1 = *(const float4*)(er + 256 + lane * 4);
            const float4 f0 = *(const float4*)(er + HH + lane * 4);
            const float4 f1 = *(const float4*)(er + HH + 256 + lane * 4);
            float dA = e0.x * h0.x + e0.y * h0.y + e0.z * h0.z + e0.w * h0.w
                     + e1.x * h1.x + e1.y * h1.y + e1.z * h1.z + e1.w * h1.w;
            float dB = f0.x * h0.x + f0.y * h0.y + f0.z * h0.z + f0.w * h0.w
                     + f1.x * h1.x + f1.y * h1.y + f1.z * h1.z + f1.w * h1.w;
#pragma unroll
            for (int off = 32; off; off >>= 1) {
                dA += __shfl_xor(dA, off);
                dB += __shfl_xor(dB, off);
            }
            const float mx = fmaxf(dA, dB);
            if (mx > m) {                      // wave-uniform branch
                const float fs = __expf(m - mx);
                l *= fs;
                c0.x *= fs; c0.y *= fs; c0.z *= fs; c0.w *= fs;
                c1.x *= fs; c1.y *= fs; c1.z *= fs; c1.w *= fs;
                m = mx;
            }
            const float pA = __expf(dA - m);
            const float pB = __expf(dB - m);
            l += pA + pB;
            c0.x += pA * e0.x + pB * f0.x; c0.y += pA * e0.y + pB * f0.y;
            c0.z += pA * e0.z + pB * f0.z; c0.w += pA * e0.w + pB * f0.w;
            c1.x += pA * e1.x + pB * f1.x; c1.y += pA * e1.y + pB * f1.y;
            c1.z += pA * e1.z + pB * f1.z; c1.w += pA * e1.w + pB * f1.w;
            er += 2 * HH;
        }
        if (lane == 0) { sh.a.m[w] = m; sh.a.l[w] = l; }
        *(float4*)&sh.a.ctx[w][lane * 4] = c0;
        *(float4*)&sh.a.ctx[w][256 + lane * 4] = c1;
        __syncthreads();
        // block-level combine of the 4 wave partials
        float M = fmaxf(fmaxf(sh.a.m[0], sh.a.m[1]), fmaxf(sh.a.m[2], sh.a.m[3]));
        float wg[4]; float ls = 0.f;
#pragma unroll
        for (int q = 0; q < 4; ++q) { wg[q] = __expf(sh.a.m[q] - M); ls += wg[q] * sh.a.l[q]; }
        const int hh = tid * 2;
        float v0 = wg[0] * sh.a.ctx[0][hh] + wg[1] * sh.a.ctx[1][hh]
                 + wg[2] * sh.a.ctx[2][hh] + wg[3] * sh.a.ctx[3][hh];
        float v1 = wg[0] * sh.a.ctx[0][hh + 1] + wg[1] * sh.a.ctx[1][hh + 1]
                 + wg[2] * sh.a.ctx[2][hh + 1] + wg[3] * sh.a.ctx[3][hh + 1];
        float* pc = pctx + ((size_t)(b * 16 + ch)) * HH;
        *(float2*)(pc + hh) = make_float2(v0, v1);
        if (tid == 0) { pm[b * 16 + ch] = M; pl[b * 16 + ch] = ls; }
    } else if (t > 0) {
        fc_unit(u - 1024, t - 1, h, W_fc, b_fc, out, sh.o.acc);
    }
}

// Fence-free combine: block b merges its 16 chunk partials -> xb[b] (bf16),
// and packs target(t) and h into xb. Identical summation order to R4.
__global__ void __launch_bounds__(256)
step_combine(int t, const float* __restrict__ target, const float* __restrict__ h,
             const float* __restrict__ pm, const float* __restrict__ pl,
             const float* __restrict__ pctx, unsigned short* __restrict__ xb) {
    const int tid = threadIdx.x;
    const int b = blockIdx.x;
    float Mb = -3.0e38f;
#pragma unroll
    for (int q2 = 0; q2 < 16; ++q2) Mb = fmaxf(Mb, pm[b * 16 + q2]);
    float wq[16]; float lsb = 0.f;
#pragma unroll
    for (int q2 = 0; q2 < 16; ++q2) {
        wq[q2] = __expf(pm[b * 16 + q2] - Mb);
        lsb += wq[q2] * pl[b * 16 + q2];
    }
    const float inv = 1.0f / lsb;
    const int h2 = tid * 2;
    float s0 = 0.f, s1 = 0.f;
#pragma unroll
    for (int q2 = 0; q2 < 16; ++q2) {
        const float* pc2 = pctx + ((size_t)(b * 16 + q2)) * HH + h2;
        s0 += wq[q2] * pc2[0];
        s1 += wq[q2] * pc2[1];
    }
    xb[b * KK + h2]     = f2bf(s0 * inv);
    xb[b * KK + h2 + 1] = f2bf(s1 * inv);
    if (tid < 128) {
        const float* tg = target + ((size_t)b * TT + t) * OO + tid * 2;
        xb[b * KK + 512 + tid * 2]     = f2bf(tg[0]);
        xb[b * KK + 512 + tid * 2 + 1] = f2bf(tg[1]);
    }
    xb[b * KK + 768 + h2]     = f2bf(h[b * HH + h2]);
    xb[b * KK + 768 + h2 + 1] = f2bf(h[b * HH + h2 + 1]);
}

// One block per h-tile (64 blocks): gates MFMA over K=1280 + cell/h update.
// Block-local only — fence-free.
__global__ void __launch_bounds__(256)
step_gates(const unsigned short* __restrict__ xb,
           const unsigned short* __restrict__ wfrag,
           const float* __restrict__ b_ih, const float* __restrict__ b_hh,
           float* __restrict__ h, float* __restrict__ c) {
    const int tid = threadIdx.x;
    const int lane = tid & 63;
    const int w = tid >> 6;
    __shared__ float g[64][32];

    const int ht = blockIdx.x;
    fx4 a0 = {0, 0, 0, 0}, a1 = {0, 0, 0, 0};
    const int bro = 16 * w + (lane & 15);
    const int kg = lane >> 4;
    const unsigned short* wf = wfrag + ((size_t)ht * 40 * 2) * 512;
    for (int kk = 0; kk < 40; ++kk) {
        bh8 av = *(const bh8*)(xb + (size_t)bro * KK + kk * 32 + kg * 8);
        bh8 b0 = *(const bh8*)(wf + (kk * 2 + 0) * 512 + lane * 8);
        bh8 b1 = *(const bh8*)(wf + (kk * 2 + 1) * 512 + lane * 8);
        a0 = __builtin_amdgcn_mfma_f32_16x16x32_bf16(av, b0, a0, 0, 0, 0);
        a1 = __builtin_amdgcn_mfma_f32_16x16x32_bf16(av, b1, a1, 0, 0, 0);
    }
    const int crow = (lane >> 4) * 4;
#pragma unroll
    for (int r = 0; r < 4; ++r) {
        g[16 * w + crow + r][lane & 15]        = a0[r];
        g[16 * w + crow + r][16 + (lane & 15)] = a1[r];
    }
    __syncthreads();
#pragma unroll
    for (int p = 0; p < 2; ++p) {
        const int idx = tid * 2 + p;
        const int b = idx >> 3, r = idx & 7;
        const int hidx = ht * 8 + r;
        float gi = g[b][r]      + b_ih[hidx]        + b_hh[hidx];
        float gf = g[b][8 + r]  + b_ih[512 + hidx]  + b_hh[512 + hidx];
        float gg = g[b][16 + r] + b_ih[1024 + hidx] + b_hh[1024 + hidx];
        float go = g[b][24 + r] + b_ih[1536 + hidx] + b_hh[1536 + hidx];
        float ig = 1.f / (1.f + __expf(-gi));
        float fg = 1.f / (1.f + __expf(-gf));
        float g2 = tanhf(gg);
        float og = 1.f / (1.f + __expf(-go));
        float cn = fg * c[b * HH + hidx] + ig * g2;
        float hn = og * tanhf(cn);
        c[b * HH + hidx] = cn;
        h[b * HH + hidx] = hn;
    }
}

__global__ void __launch_bounds__(256)
fc_final(const float* __restrict__ h, const float* __restrict__ W_fc,
         const float* __restrict__ b_fc, float* __restrict__ out) {
    __shared__ float acc[4][64];
    fc_unit(blockIdx.x, TT - 1, h, W_fc, b_fc, out, acc);
}

extern "C" void kernel_launch(void* const* d_in, const int* in_sizes, int n_in,
                              void* d_out, int out_size, void* d_ws, size_t ws_size,
                              hipStream_t stream) {
    const float* enc    = (const float*)d_in[0];
    const float* hidden = (const float*)d_in[1];
    const float* cellp  = (const float*)d_in[2];
    const float* target = (const float*)d_in[3];
    const float* W_ih   = (const float*)d_in[4];
    const float* W_hh   = (const float*)d_in[5];
    const float* b_ih   = (const float*)d_in[6];
    const float* b_hh   = (const float*)d_in[7];
    const float* W_fc   = (const float*)d_in[8];
    const float* b_fc   = (const float*)d_in[9];
    float* out = (float*)d_out;

    char* base = (char*)d_ws;
    float* h              = (float*)(base + 0);          // 64*512 f32
    float* c              = (float*)(base + 131072);     // 64*512 f32
    unsigned short* wfrag = (unsigned short*)(base + 262144);   // 5,242,880 B
    unsigned short* xb    = (unsigned short*)(base + 5505024);  // 64*1280 bf16
    float* pm             = (float*)(base + 5668864);    // 64*16
    float* pl             = (float*)(base + 5672960);    // 64*16
    float* pctx           = (float*)(base + 5677056);    // 64*16*512 f32
    // end: 5677056 + 2097152 = 7774208 bytes

    hipLaunchKernelGGL(prep_weights, dim3(1280), dim3(256), 0, stream, W_ih, W_hh, wfrag);
    hipLaunchKernelGGL(prep_misc, dim3(256), dim3(256), 0, stream,
                       hidden, cellp, h, c);

    for (int t = 0; t < TT; ++t) {
        hipLaunchKernelGGL(step_attnp, dim3(1280), dim3(256), 0, stream,
                           t, enc, h, pm, pl, pctx, W_fc, b_fc, out);
        hipLaunchKernelGGL(step_combine, dim3(64), dim3(256), 0, stream,
                           t, target, h, pm, pl, pctx, xb);
        hipLaunchKernelGGL(step_gates, dim3(64), dim3(256), 0, stream,
                           xb, wfrag, b_ih, b_hh, h, c);
    }
    hipLaunchKernelGGL(fc_final, dim3(256), dim3(256), 0, stream,
                       h, W_fc, b_fc, out);
}

// Round 9
// 10526.549 us; speedup vs baseline: 13.6485x; 1.0391x over previous
//
#include <hip/hip_runtime.h>

#define HH 512
#define OO 256
#define BB 64
#define SS 1024
#define TT 256
#define KK 1280   // H(ctx) + O(target) + H(h)

typedef __attribute__((ext_vector_type(8))) short bh8;
typedef __attribute__((ext_vector_type(8))) _Float16 hf8;
typedef __attribute__((ext_vector_type(4))) float fx4;

__device__ __forceinline__ unsigned short f2bf(float x) {
    union { float f; unsigned int u; } v; v.f = x;
    unsigned int r = v.u + 0x7fffu + ((v.u >> 16) & 1u);
    return (unsigned short)(r >> 16);
}
__device__ __forceinline__ float bf2f(unsigned short s) {
    union { unsigned int u; float f; } z; z.u = ((unsigned int)s) << 16; return z.f;
}

// Pack W_cat = [W_ih | W_hh] (j-permuted; see round-0 comment) into MFMA
// B-fragment-major bf16 hi/lo split: W = hi + lo, lo = bf16(W - f32(hi)).
__global__ void prep_weights(const float* __restrict__ W_ih,
                             const float* __restrict__ W_hh,
                             unsigned short* __restrict__ wfH,
                             unsigned short* __restrict__ wfL) {
    int g = blockIdx.x * 256 + threadIdx.x;     // 64*40*2*64 = 327680 groups
    if (g >= 64 * 40 * 2 * 64) return;
    int lane = g & 63;
    int nt = (g >> 6) & 1;
    int kk = (g >> 7) % 40;
    int ht = (g >> 7) / 40;
    int c = nt * 16 + (lane & 15);
    int gate = c >> 3, rr = c & 7;
    int j = gate * 512 + ht * 8 + rr;
    int kbase = kk * 32 + (lane >> 4) * 8;
    unsigned short* dh = wfH + (size_t)g * 8;
    unsigned short* dl = wfL + (size_t)g * 8;
#pragma unroll
    for (int r = 0; r < 8; ++r) {
        int k = kbase + r;
        float v = (k < 768) ? W_ih[(size_t)j * 768 + k]
                            : W_hh[(size_t)j * 512 + (k - 768)];
        unsigned short hi = f2bf(v);
        dh[r] = hi;
        dl[r] = f2bf(v - bf2f(hi));
    }
}

__global__ void prep_misc(const float* __restrict__ hidden,
                          const float* __restrict__ cell,
                          float* __restrict__ h, float* __restrict__ c) {
    const int total = 32768 + 32768;
    for (int i = blockIdx.x * 256 + threadIdx.x; i < total; i += gridDim.x * 256) {
        if (i < 32768) h[i] = hidden[i];
        else           c[i - 32768] = cell[i - 32768];
    }
}

// One-time fp32 -> fp16 convert of encoder_outputs (33.5M elems, 8/thread).
// fp16 (10 mantissa bits) keeps score error ~4x below bf16; enc ~N(0,1) is
// far from fp16 range limits.
__global__ void prep_enc(const float* __restrict__ enc,
                         _Float16* __restrict__ ench) {
    const size_t i = ((size_t)blockIdx.x * 256 + threadIdx.x) * 8;
    const float4 a = *(const float4*)(enc + i);
    const float4 b = *(const float4*)(enc + i + 4);
    hf8 o;
    o[0] = (_Float16)a.x; o[1] = (_Float16)a.y;
    o[2] = (_Float16)a.z; o[3] = (_Float16)a.w;
    o[4] = (_Float16)b.x; o[5] = (_Float16)b.y;
    o[6] = (_Float16)b.z; o[7] = (_Float16)b.w;
    *(hf8*)(ench + i) = o;
}

// FC for one (b, oq) unit; fp32 W_fc rows, summation order as R4-R7.
__device__ __forceinline__ void fc_unit(int v, int tprev,
                                        const float* __restrict__ h,
                                        const float* __restrict__ W_fc,
                                        const float* __restrict__ b_fc,
                                        float* __restrict__ out,
                                        float (*shacc)[64]) {
    const int tid = threadIdx.x;
    const int b = v >> 2, oq = v & 3;
    const int ol = tid & 63, kq = tid >> 6;
    const int o = oq * 64 + ol;
    float acc = 0.f;
    const float* hp = h + b * HH + kq * 128;
    const float* wp = W_fc + (size_t)o * HH + kq * 128;
#pragma unroll 8
    for (int k2 = 0; k2 < 128; ++k2) acc += hp[k2] * wp[k2];
    shacc[kq][ol] = acc;
    __syncthreads();
    if (tid < 64) {
        float vv = shacc[0][tid] + shacc[1][tid]
                 + shacc[2][tid] + shacc[3][tid] + b_fc[oq * 64 + tid];
        out[((size_t)b * TT + tprev) * OO + oq * 64 + tid] = vv;
    }
}

// Fence-free attention partials (template: fp16 or fp32 enc reads).
// Blocks 0..1023: unit (b, ch) -> pm/pl/pctx. Blocks 1024..1279: FC(t-1).
template <int ENCF16>
__global__ void __launch_bounds__(256)
step_attnp(int t, const float* __restrict__ enc,
           const _Float16* __restrict__ ench,
           const float* __restrict__ h,
           float* __restrict__ pm, float* __restrict__ pl,
           float* __restrict__ pctx,
           const float* __restrict__ W_fc, const float* __restrict__ b_fc,
           float* __restrict__ out) {
    const int tid = threadIdx.x;
    const int lane = tid & 63;
    const int w = tid >> 6;

    __shared__ union {
        struct { float m[4]; float l[4]; float ctx[4][512]; } a;
        struct { float acc[4][64]; } o;
    } sh;

    const int u = blockIdx.x;
    if (u < 1024) {
        const int b = u >> 4, ch = u & 15;
        float m = -3.0e38f, l = 0.f;
        if (ENCF16) {
            const float* hb = h + b * HH + lane * 8;
            const float4 h0 = *(const float4*)hb;
            const float4 h1 = *(const float4*)(hb + 4);
            float cx[8];
#pragma unroll
            for (int j = 0; j < 8; ++j) cx[j] = 0.f;
            const _Float16* er =
                ench + ((size_t)(b * SS + ch * 64 + w * 16)) * HH + lane * 8;
            for (int rp = 0; rp < 8; ++rp) {
                const hf8 ev = *(const hf8*)er;
                const hf8 fv = *(const hf8*)(er + HH);
                float e[8], f[8];
#pragma unroll
                for (int j = 0; j < 8; ++j) {
                    e[j] = (float)ev[j];
                    f[j] = (float)fv[j];
                }
                float dA = e[0]*h0.x + e[1]*h0.y + e[2]*h0.z + e[3]*h0.w
                         + e[4]*h1.x + e[5]*h1.y + e[6]*h1.z + e[7]*h1.w;
                float dB = f[0]*h0.x + f[1]*h0.y + f[2]*h0.z + f[3]*h0.w
                         + f[4]*h1.x + f[5]*h1.y + f[6]*h1.z + f[7]*h1.w;
#pragma unroll
                for (int off = 32; off; off >>= 1) {
                    dA += __shfl_xor(dA, off);
                    dB += __shfl_xor(dB, off);
                }
                const float mx = fmaxf(dA, dB);
                if (mx > m) {                      // wave-uniform branch
                    const float fs = __expf(m - mx);
                    l *= fs;
#pragma unroll
                    for (int j = 0; j < 8; ++j) cx[j] *= fs;
                    m = mx;
                }
                const float pA = __expf(dA - m);
                const float pB = __expf(dB - m);
                l += pA + pB;
#pragma unroll
                for (int j = 0; j < 8; ++j) cx[j] += pA * e[j] + pB * f[j];
                er += 2 * HH;
            }
            if (lane == 0) { sh.a.m[w] = m; sh.a.l[w] = l; }
            *(float4*)&sh.a.ctx[w][lane * 8]     = make_float4(cx[0], cx[1], cx[2], cx[3]);
            *(float4*)&sh.a.ctx[w][lane * 8 + 4] = make_float4(cx[4], cx[5], cx[6], cx[7]);
        } else {
            const float4 h0 = *(const float4*)(h + b * HH + lane * 4);
            const float4 h1 = *(const float4*)(h + b * HH + 256 + lane * 4);
            float4 c0 = {0, 0, 0, 0}, c1 = {0, 0, 0, 0};
            const float* er = enc + ((size_t)(b * SS + ch * 64 + w * 16)) * HH;
            for (int rp = 0; rp < 8; ++rp) {
                const float4 e0 = *(const float4*)(er + lane * 4);
                const float4 e1 = *(const float4*)(er + 256 + lane * 4);
                const float4 f0 = *(const float4*)(er + HH + lane * 4);
                const float4 f1 = *(const float4*)(er + HH + 256 + lane * 4);
                float dA = e0.x * h0.x + e0.y * h0.y + e0.z * h0.z + e0.w * h0.w
                         + e1.x * h1.x + e1.y * h1.y + e1.z * h1.z + e1.w * h1.w;
                float dB = f0.x * h0.x + f0.y * h0.y + f0.z * h0.z + f0.w * h0.w
                         + f1.x * h1.x + f1.y * h1.y + f1.z * h1.z + f1.w * h1.w;
#pragma unroll
                for (int off = 32; off; off >>= 1) {
                    dA += __shfl_xor(dA, off);
                    dB += __shfl_xor(dB, off);
                }
                const float mx = fmaxf(dA, dB);
                if (mx > m) {
                    const float fs = __expf(m - mx);
                    l *= fs;
                    c0.x *= fs; c0.y *= fs; c0.z *= fs; c0.w *= fs;
                    c1.x *= fs; c1.y *= fs; c1.z *= fs; c1.w *= fs;
                    m = mx;
                }
                const float pA = __expf(dA - m);
                const float pB = __expf(dB - m);
                l += pA + pB;
                c0.x += pA * e0.x + pB * f0.x; c0.y += pA * e0.y + pB * f0.y;
                c0.z += pA * e0.z + pB * f0.z; c0.w += pA * e0.w + pB * f0.w;
                c1.x += pA * e1.x + pB * f1.x; c1.y += pA * e1.y + pB * f1.y;
                c1.z += pA * e1.z + pB * f1.z; c1.w += pA * e1.w + pB * f1.w;
                er += 2 * HH;
            }
            if (lane == 0) { sh.a.m[w] = m; sh.a.l[w] = l; }
            *(float4*)&sh.a.ctx[w][lane * 4] = c0;
            *(float4*)&sh.a.ctx[w][256 + lane * 4] = c1;
        }
        __syncthreads();
        // block-level combine of the 4 wave partials
        float M = fmaxf(fmaxf(sh.a.m[0], sh.a.m[1]), fmaxf(sh.a.m[2], sh.a.m[3]));
        float wg[4]; float ls = 0.f;
#pragma unroll
        for (int q = 0; q < 4; ++q) { wg[q] = __expf(sh.a.m[q] - M); ls += wg[q] * sh.a.l[q]; }
        const int hh = tid * 2;
        float v0 = wg[0] * sh.a.ctx[0][hh] + wg[1] * sh.a.ctx[1][hh]
                 + wg[2] * sh.a.ctx[2][hh] + wg[3] * sh.a.ctx[3][hh];
        float v1 = wg[0] * sh.a.ctx[0][hh + 1] + wg[1] * sh.a.ctx[1][hh + 1]
                 + wg[2] * sh.a.ctx[2][hh + 1] + wg[3] * sh.a.ctx[3][hh + 1];
        float* pc = pctx + ((size_t)(b * 16 + ch)) * HH;
        *(float2*)(pc + hh) = make_float2(v0, v1);
        if (tid == 0) { pm[b * 16 + ch] = M; pl[b * 16 + ch] = ls; }
    } else if (t > 0) {
        fc_unit(u - 1024, t - 1, h, W_fc, b_fc, out, sh.o.acc);
    }
}

// Fence-free combine: block b merges 16 chunk partials -> xb hi/lo (bf16
// split), packs target(t) and h. Same summation order as before.
__global__ void __launch_bounds__(256)
step_combine(int t, const float* __restrict__ target, const float* __restrict__ h,
             const float* __restrict__ pm, const float* __restrict__ pl,
             const float* __restrict__ pctx,
             unsigned short* __restrict__ xbh, unsigned short* __restrict__ xbl) {
    const int tid = threadIdx.x;
    const int b = blockIdx.x;
    float Mb = -3.0e38f;
#pragma unroll
    for (int q2 = 0; q2 < 16; ++q2) Mb = fmaxf(Mb, pm[b * 16 + q2]);
    float wq[16]; float lsb = 0.f;
#pragma unroll
    for (int q2 = 0; q2 < 16; ++q2) {
        wq[q2] = __expf(pm[b * 16 + q2] - Mb);
        lsb += wq[q2] * pl[b * 16 + q2];
    }
    const float inv = 1.0f / lsb;
    const int h2 = tid * 2;
    float s0 = 0.f, s1 = 0.f;
#pragma unroll
    for (int q2 = 0; q2 < 16; ++q2) {
        const float* pc2 = pctx + ((size_t)(b * 16 + q2)) * HH + h2;
        s0 += wq[q2] * pc2[0];
        s1 += wq[q2] * pc2[1];
    }
    s0 *= inv; s1 *= inv;
    unsigned short a0 = f2bf(s0), a1 = f2bf(s1);
    xbh[b * KK + h2]     = a0;  xbl[b * KK + h2]     = f2bf(s0 - bf2f(a0));
    xbh[b * KK + h2 + 1] = a1;  xbl[b * KK + h2 + 1] = f2bf(s1 - bf2f(a1));
    if (tid < 128) {
        const float* tg = target + ((size_t)b * TT + t) * OO + tid * 2;
        unsigned short t0 = f2bf(tg[0]), t1 = f2bf(tg[1]);
        xbh[b * KK + 512 + tid * 2]     = t0;
        xbh[b * KK + 512 + tid * 2 + 1] = t1;
        xbl[b * KK + 512 + tid * 2]     = f2bf(tg[0] - bf2f(t0));
        xbl[b * KK + 512 + tid * 2 + 1] = f2bf(tg[1] - bf2f(t1));
    }
    const float hv0 = h[b * HH + h2], hv1 = h[b * HH + h2 + 1];
    unsigned short g0 = f2bf(hv0), g1 = f2bf(hv1);
    xbh[b * KK + 768 + h2]     = g0;  xbl[b * KK + 768 + h2]     = f2bf(hv0 - bf2f(g0));
    xbh[b * KK + 768 + h2 + 1] = g1;  xbl[b * KK + 768 + h2 + 1] = f2bf(hv1 - bf2f(g1));
}

// One block per h-tile: split-bf16 gates GEMM (xh*Wh + xl*Wh + xh*Wl) + cell.
__global__ void __launch_bounds__(256)
step_gates(const unsigned short* __restrict__ xbh,
           const unsigned short* __restrict__ xbl,
           const unsigned short* __restrict__ wfH,
           const unsigned short* __restrict__ wfL,
           const float* __restrict__ b_ih, const float* __restrict__ b_hh,
           float* __restrict__ h, float* __restrict__ c) {
    const int tid = threadIdx.x;
    const int lane = tid & 63;
    const int w = tid >> 6;
    __shared__ float g[64][32];

    const int ht = blockIdx.x;
    fx4 a0 = {0, 0, 0, 0}, a1 = {0, 0, 0, 0};
    const int bro = 16 * w + (lane & 15);
    const int kg = lane >> 4;
    const size_t wbase = (size_t)ht * 40 * 2 * 512;
    for (int kk = 0; kk < 40; ++kk) {
        const size_t aoff = (size_t)bro * KK + kk * 32 + kg * 8;
        bh8 avh = *(const bh8*)(xbh + aoff);
        bh8 avl = *(const bh8*)(xbl + aoff);
        bh8 b0h = *(const bh8*)(wfH + wbase + (kk * 2 + 0) * 512 + lane * 8);
        bh8 b1h = *(const bh8*)(wfH + wbase + (kk * 2 + 1) * 512 + lane * 8);
        bh8 b0l = *(const bh8*)(wfL + wbase + (kk * 2 + 0) * 512 + lane * 8);
        bh8 b1l = *(const bh8*)(wfL + wbase + (kk * 2 + 1) * 512 + lane * 8);
        a0 = __builtin_amdgcn_mfma_f32_16x16x32_bf16(avh, b0h, a0, 0, 0, 0);
        a0 = __builtin_amdgcn_mfma_f32_16x16x32_bf16(avl, b0h, a0, 0, 0, 0);
        a0 = __builtin_amdgcn_mfma_f32_16x16x32_bf16(avh, b0l, a0, 0, 0, 0);
        a1 = __builtin_amdgcn_mfma_f32_16x16x32_bf16(avh, b1h, a1, 0, 0, 0);
        a1 = __builtin_amdgcn_mfma_f32_16x16x32_bf16(avl, b1h, a1, 0, 0, 0);
        a1 = __builtin_amdgcn_mfma_f32_16x16x32_bf16(avh, b1l, a1, 0, 0, 0);
    }
    const int crow = (lane >> 4) * 4;
#pragma unroll
    for (int r = 0; r < 4; ++r) {
        g[16 * w + crow + r][lane & 15]        = a0[r];
        g[16 * w + crow + r][16 + (lane & 15)] = a1[r];
    }
    __syncthreads();
#pragma unroll
    for (int p = 0; p < 2; ++p) {
        const int idx = tid * 2 + p;
        const int b = idx >> 3, r = idx & 7;
        const int hidx = ht * 8 + r;
        float gi = g[b][r]      + b_ih[hidx]        + b_hh[hidx];
        float gf = g[b][8 + r]  + b_ih[512 + hidx]  + b_hh[512 + hidx];
        float gg = g[b][16 + r] + b_ih[1024 + hidx] + b_hh[1024 + hidx];
        float go = g[b][24 + r] + b_ih[1536 + hidx] + b_hh[1536 + hidx];
        float ig = 1.f / (1.f + __expf(-gi));
        float fg = 1.f / (1.f + __expf(-gf));
        float g2 = tanhf(gg);
        float og = 1.f / (1.f + __expf(-go));
        float cn = fg * c[b * HH + hidx] + ig * g2;
        float hn = og * tanhf(cn);
        c[b * HH + hidx] = cn;
        h[b * HH + hidx] = hn;
    }
}

__global__ void __launch_bounds__(256)
fc_final(const float* __restrict__ h, const float* __restrict__ W_fc,
         const float* __restrict__ b_fc, float* __restrict__ out) {
    __shared__ float acc[4][64];
    fc_unit(blockIdx.x, TT - 1, h, W_fc, b_fc, out, acc);
}

extern "C" void kernel_launch(void* const* d_in, const int* in_sizes, int n_in,
                              void* d_out, int out_size, void* d_ws, size_t ws_size,
                              hipStream_t stream) {
    const float* enc    = (const float*)d_in[0];
    const float* hidden = (const float*)d_in[1];
    const float* cellp  = (const float*)d_in[2];
    const float* target = (const float*)d_in[3];
    const float* W_ih   = (const float*)d_in[4];
    const float* W_hh   = (const float*)d_in[5];
    const float* b_ih   = (const float*)d_in[6];
    const float* b_hh   = (const float*)d_in[7];
    const float* W_fc   = (const float*)d_in[8];
    const float* b_fc   = (const float*)d_in[9];
    float* out = (float*)d_out;

    char* base = (char*)d_ws;
    float* h              = (float*)(base + 0);          // 131,072 B
    float* c              = (float*)(base + 131072);     // 131,072 B
    unsigned short* wfH   = (unsigned short*)(base + 262144);    // 5,242,880 B
    unsigned short* wfL   = (unsigned short*)(base + 5505024);   // 5,242,880 B
    unsigned short* xbh   = (unsigned short*)(base + 10747904);  // 163,840 B
    unsigned short* xbl   = (unsigned short*)(base + 10911744);  // 163,840 B
    float* pm             = (float*)(base + 11075584);   // 4,096 B
    float* pl             = (float*)(base + 11079680);   // 4,096 B
    float* pctx           = (float*)(base + 11083776);   // 2,097,152 B
    _Float16* ench        = (_Float16*)(base + 13180928);        // 67,108,864 B
    const size_t NEED_H = 13180928ULL + 67108864ULL;     // 80,289,792 B

    const bool use_ench = (ws_size >= NEED_H);

    prep_weights<<<dim3(1280), dim3(256), 0, stream>>>(W_ih, W_hh, wfH, wfL);
    prep_misc<<<dim3(256), dim3(256), 0, stream>>>(hidden, cellp, h, c);
    if (use_ench)
        prep_enc<<<dim3(16384), dim3(256), 0, stream>>>(enc, ench);

    for (int t = 0; t < TT; ++t) {
        if (use_ench)
            step_attnp<1><<<dim3(1280), dim3(256), 0, stream>>>(
                t, enc, ench, h, pm, pl, pctx, W_fc, b_fc, out);
        else
            step_attnp<0><<<dim3(1280), dim3(256), 0, stream>>>(
                t, enc, ench, h, pm, pl, pctx, W_fc, b_fc, out);
        step_combine<<<dim3(64), dim3(256), 0, stream>>>(
            t, target, h, pm, pl, pctx, xbh, xbl);
        step_gates<<<dim3(64), dim3(256), 0, stream>>>(
            xbh, xbl, wfH, wfL, b_ih, b_hh, h, c);
    }
    fc_final<<<dim3(256), dim3(256), 0, stream>>>(h, W_fc, b_fc, out);
}